// Round 4
// baseline (30.845 us; speedup 1.0000x reference)
//
#include <hip/hip_runtime.h>
#include <cstdint>

namespace {

constexpr int N    = 20000;   // nodes
constexpr int D    = 128;     // feature dim
constexpr int DEG  = 32;      // neighbors per node
constexpr int BB   = 1024;    // batch
constexpr int T    = 8;       // walk_times
constexpr int NW   = (N + 31) / 32;  // 625 mask words
constexpr int MAXC = 384;     // list bound (true max 32 + 7*32 = 256, +32 slack)
constexpr int NTHR = 256;     // 4 waves

__device__ __forceinline__ uint32_t rotl32(uint32_t x, int n) {
  return (x << n) | (x >> (32 - n));
}

// Threefry-2x32, 20 rounds (Random123 / JAX threefry2x32_p).
__device__ __forceinline__ void threefry2x32(uint32_t k0, uint32_t k1,
                                             uint32_t x0, uint32_t x1,
                                             uint32_t& o0, uint32_t& o1) {
  const uint32_t ks2 = k0 ^ k1 ^ 0x1BD11BDAu;
  x0 += k0; x1 += k1;
#define TF_ROUND(r) { x0 += x1; x1 = rotl32(x1, (r)); x1 ^= x0; }
  TF_ROUND(13) TF_ROUND(15) TF_ROUND(26) TF_ROUND(6)
  x0 += k1;  x1 += ks2 + 1u;
  TF_ROUND(17) TF_ROUND(29) TF_ROUND(16) TF_ROUND(24)
  x0 += ks2; x1 += k0 + 2u;
  TF_ROUND(13) TF_ROUND(15) TF_ROUND(26) TF_ROUND(6)
  x0 += k0;  x1 += k1 + 3u;
  TF_ROUND(17) TF_ROUND(29) TF_ROUND(16) TF_ROUND(24)
  x0 += k1;  x1 += ks2 + 4u;
  TF_ROUND(13) TF_ROUND(15) TF_ROUND(26) TF_ROUND(6)
  x0 += ks2; x1 += k0 + 5u;
#undef TF_ROUND
  o0 = x0; o1 = x1;
}

// Exact jax.random.gumbel f32 pipeline (step 0 only): mant = top 23 bits;
// u = mant*2^-23 (or f32 tiny); g = -fl32(log(fl32(-log(u)))).
__device__ __forceinline__ float gumbel_f32(uint32_t bits) {
  const uint32_t mant = bits >> 9;
  const float u = (mant == 0u) ? 1.17549435e-38f
                               : (__uint_as_float(0x3F800000u | mant) - 1.0f);
  const float inner = -(float)log((double)u);
  return -(float)log((double)inner);
}

__global__ __launch_bounds__(NTHR)
void walk_kernel(const float* __restrict__ features,
                 const float* __restrict__ W,
                 const float* __restrict__ bptr,
                 const int*   __restrict__ neighbors,
                 const int*   __restrict__ train_index,
                 int* __restrict__ out)
{
  __shared__ uint32_t candM[NW];    // "ever was a candidate" (never cleared; see note)
  __shared__ uint32_t chosenM[NW];  // chosen/visited (monotone)
  __shared__ int      lst[2][MAXC];
  __shared__ float    val0[DEG];    // step-0 scores only (val==1 for all later steps)
  __shared__ int      cnts[2];
  __shared__ int      pcnt;
  __shared__ int      pendC[16];    // chosen-but-listed candidates (<=9)
  __shared__ float    pendV[16];
  __shared__ uint32_t skey[T][2];
  __shared__ float    sxSh;
  __shared__ float    syArr[DEG];
  __shared__ int      nbSelf[DEG];
  __shared__ uint32_t redK[4];
  __shared__ float    redV[4];
  __shared__ int      redC[4];
  __shared__ int      newNodeSh;

  const int tid  = threadIdx.x;
  const int lane = tid & 63;
  const int wv   = tid >> 6;
  const int r    = blockIdx.x;
  const int self = train_index[r];
  const uint32_t rN = (uint32_t)(r * N);

  for (int i = tid; i < NW; i += NTHR) { candM[i] = 0u; chosenM[i] = 0u; }
  if (tid < T) {  // step keys: jax.random.split(key(42), 8), partitionable
    uint32_t o0, o1;
    threefry2x32(0u, 42u, 0u, (uint32_t)tid, o0, o1);
    skey[tid][0] = o0; skey[tid][1] = o1;
  }
  if (tid == 0) { cnts[0] = 0; cnts[1] = 0; }
  if (tid < DEG) nbSelf[tid] = neighbors[(size_t)self * DEG + tid];
  __syncthreads();

  // ---- step-0 scores (fold order bit-identical to the passing version) ----
  const float bval = bptr[0];
  if (tid < 64) {                 // wave 0: sx = dot(frow, Wx), 64-lane tree
    const float* frow = features + (size_t)self * D;
    float acc = frow[tid] * W[tid] + frow[tid + 64] * W[tid + 64];
    for (int m = 1; m < 64; m <<= 1) acc += __shfl_xor(acc, m);
    if (tid == 0) sxSh = acc;
  } else if (tid < 64 + DEG) {    // wave 1: 32 serial sy folds (1 thread/neighbor)
    const int j = tid - 64;
    const float* g  = features + (size_t)nbSelf[j] * D;
    const float* wy = W + D;
    float a = 0.0f;
    for (int d = 0; d < D; d += 4) {
      const float4 f = *reinterpret_cast<const float4*>(g + d);
      const float4 w = *reinterpret_cast<const float4*>(wy + d);
      a += f.x * w.x; a += f.y * w.y; a += f.z * w.z; a += f.w * w.w;
    }
    syArr[j] = a;
  }
  __syncthreads();
  if (tid < DEG) {  // build step-0 list: {c != self : s_c > 0}, dedup via candM
    const int nbj = nbSelf[tid];
    const float s = fmaxf((sxSh + syArr[tid]) + bval, 0.0f);
    if (nbj != self && s > 0.0f) {
      const uint32_t w = (uint32_t)nbj >> 5, bit = 1u << (nbj & 31);
      const uint32_t old = atomicOr(&candM[w], bit);
      if (!(old & bit)) {
        const int p = atomicAdd(&cnts[0], 1);
        lst[0][p] = nbj; val0[p] = s;
      }
    }
  }
  __syncthreads();
  if (tid == 0) {
    chosenM[(uint32_t)self >> 5] |= 1u << (self & 31);   // chosen = self_oh
    if (cnts[0] == 0) {  // pre-scan fallback mutates the carry: candi = self_oh
      lst[0][0] = self; val0[0] = 1.0f; cnts[0] = 1;
      candM[(uint32_t)self >> 5] |= 1u << (self & 31);
    }
  }
  __syncthreads();

  int cur = 0;
  for (int k = 0; k < T; ++k) {
    const int cnt = cnts[cur];
    const uint32_t kk0 = skey[k][0], kk1 = skey[k][1];

    // ---- argmax (empty list -> bc stays INT_MAX -> fallback to self) ----
    if (k == 0) {  // scored step: v = log(s) + gumbel, exact f32 pipeline
      float bv = -__builtin_huge_valf(); int bc = 0x7FFFFFFF;
      for (int i = tid; i < cnt; i += NTHR) {
        const int c = lst[cur][i];
        uint32_t o0, o1;
        threefry2x32(kk0, kk1, 0u, rN + (uint32_t)c, o0, o1);
        const float v = (float)log((double)val0[i]) + gumbel_f32(o0 ^ o1);
        if (v > bv || (v == bv && c < bc)) { bv = v; bc = c; }
      }
      for (int m = 1; m < 64; m <<= 1) {
        const float ov = __shfl_xor(bv, m); const int oc = __shfl_xor(bc, m);
        if (ov > bv || (ov == bv && oc < bc)) { bv = ov; bc = oc; }
      }
      if (lane == 0) { redV[wv] = bv; redC[wv] = bc; }
    } else {
      // steps>=1: logp==0 and gumbel strictly monotone in top-23-bit mantissa
      // -> argmax(g) == argmax(mant), ties -> smallest index (jnp first-occurrence)
      uint32_t bk = 0u; int bc = 0x7FFFFFFF;
      for (int i = tid; i < cnt; i += NTHR) {
        const int c = lst[cur][i];
        uint32_t o0, o1;
        threefry2x32(kk0, kk1, 0u, rN + (uint32_t)c, o0, o1);
        const uint32_t key = (o0 ^ o1) >> 9;
        if (key > bk || (key == bk && c < bc)) { bk = key; bc = c; }
      }
      for (int m = 1; m < 64; m <<= 1) {
        const uint32_t ok = (uint32_t)__shfl_xor((int)bk, m);
        const int      oc = __shfl_xor(bc, m);
        if (ok > bk || (ok == bk && oc < bc)) { bk = ok; bc = oc; }
      }
      if (lane == 0) { redK[wv] = bk; redC[wv] = bc; }
    }
    __syncthreads();

    if (tid == 0) {  // combine 4 wave partials (associative: max + total-order tie)
      int nn;
      if (k == 0) {
        float bv = redV[0]; int bc = redC[0];
        for (int q = 1; q < 4; ++q) {
          const float ov = redV[q]; const int oc = redC[q];
          if (ov > bv || (ov == bv && oc < bc)) { bv = ov; bc = oc; }
        }
        nn = (bc == 0x7FFFFFFF) ? self : bc;
      } else {
        uint32_t bk = redK[0]; int bc = redC[0];
        for (int q = 1; q < 4; ++q) {
          const uint32_t ok = redK[q]; const int oc = redC[q];
          if (ok > bk || (ok == bk && oc < bc)) { bk = ok; bc = oc; }
        }
        nn = (bc == 0x7FFFFFFF) ? self : bc;
      }
      newNodeSh = nn;
      out[r * (T + 1) + k + 1] = nn;
      chosenM[(uint32_t)nn >> 5] |= 1u << (nn & 31);   // chosen |= new (before update)
      cnts[cur ^ 1] = 0; pcnt = 0;
    }
    __syncthreads();

    const int nn = newNodeSh;
    int nb = 0;
    if (tid < DEG) nb = neighbors[(size_t)nn * DEG + tid];  // latency hides under (a1)

    // (a1) retention, no adj needed: !ch -> keep always ((v-0)+ad >= v > 0);
    //      ch -> pending (<=9), resolved after nb arrives.
    //      NOTE: candM needs no clearing — every dropped node is chosen, and
    //      chosen nodes are permanently excluded from (b) re-adds via chosenM.
    for (int i = tid; i < cnt; i += NTHR) {
      const int c = lst[cur][i];
      const uint32_t w = (uint32_t)c >> 5, bit = 1u << (c & 31);
      const bool keep = !(chosenM[w] & bit);
      const uint64_t act = __ballot(1);
      const uint64_t mk  = __ballot(keep);
      const int ldr = (int)(__ffsll((unsigned long long)act) - 1);
      int base = 0;
      if (lane == ldr) base = atomicAdd(&cnts[cur ^ 1], (int)__popcll(mk));
      base = __shfl(base, ldr);
      if (keep) {
        lst[cur ^ 1][base + (int)__popcll(mk & ((1ULL << lane) - 1ULL))] = c;
      } else {
        const int q = atomicAdd(&pcnt, 1);
        pendC[q] = c; pendV[q] = (k == 0) ? val0[i] : 1.0f;
      }
    }
    __syncthreads();

    if (tid < DEG) {  // wave 0 holds nb
      // resolve pending: exact reference f32 semantics (v - 1) + ad > 0
      const int pn = pcnt;
      for (int q = 0; q < pn; ++q) {
        const int p = pendC[q];
        const bool isadj = __any(nb == p);
        if (tid == 0) {
          if ((pendV[q] - 1.0f) + (isadj ? 1.0f : 0.0f) > 0.0f) {
            const int pp = atomicAdd(&cnts[cur ^ 1], 1);
            lst[cur ^ 1][pp] = p;
          }
        }
      }
      // (b) fresh adj members: add iff not chosen and never-listed (dedup by candM)
      const uint32_t w = (uint32_t)nb >> 5, bit = 1u << (nb & 31);
      if (!(chosenM[w] & bit) && !(candM[w] & bit)) {
        const uint32_t old = atomicOr(&candM[w], bit);
        if (!(old & bit)) {
          const int pp = atomicAdd(&cnts[cur ^ 1], 1);
          lst[cur ^ 1][pp] = nb;
        }
      }
    }
    __syncthreads();
    cur ^= 1;
  }
  if (tid == 0) out[r * (T + 1)] = self;
}

}  // namespace

extern "C" void kernel_launch(void* const* d_in, const int* in_sizes, int n_in,
                              void* d_out, int out_size, void* d_ws, size_t ws_size,
                              hipStream_t stream) {
  const float* features  = (const float*)d_in[0];
  const float* W         = (const float*)d_in[1];
  const float* b         = (const float*)d_in[2];
  const int*   neighbors = (const int*)d_in[3];
  const int*   tindex    = (const int*)d_in[4];
  int* out = (int*)d_out;

  hipLaunchKernelGGL(walk_kernel, dim3(BB), dim3(NTHR), 0, stream,
                     features, W, b, neighbors, tindex, out);
}